// Round 9
// baseline (465.070 us; speedup 1.0000x reference)
//
#include <hip/hip_runtime.h>
#include <hip/hip_bf16.h>

typedef short bf16x8 __attribute__((ext_vector_type(8)));   // 8 bf16 in 4 VGPRs
typedef float f32x4  __attribute__((ext_vector_type(4)));

constexpr int B = 8, T = 10, F = 64, CO = 256;
constexpr long IMGPIX      = 48 * 48;                // 2304
constexpr long STATE_ELEMS = (long)B * IMGPIX * F;   // 1,179,648
constexpr float BN_INVN    = 1.0f / (float)(B * T * IMGPIX);

__device__ __forceinline__ float  b2f(ushort u) { return __uint_as_float(((unsigned)u) << 16); }
__device__ __forceinline__ ushort f2b(float f) {
    unsigned x = __float_as_uint(f);
    return (ushort)((x + 0x7fffu + ((x >> 16) & 1u)) >> 16);   // RNE
}
__device__ __forceinline__ float hsig(float x) { return fminf(fmaxf(0.2f * x + 0.5f, 0.f), 1.f); }
__device__ __forceinline__ float tanh_f(float v) {
    return 1.f - 2.f / (__expf(2.f * v) + 1.f);    // exact at +/-inf, ~1e-6 err
}

union V16 { uint4 u; bf16x8 b; };

// ---------------------------------------------------------------------------
// Fused ConvLSTM step, M=96 / quarter-N version.
// Grid = 768: (img 0..7) x (row-pair y2 0..23) x (f-quarter q 0..3).
// Block = 256 threads, 4 waves; wave wid = gate g in {i,f,c,o}; its MFMA
// N-tile is ntile = g*4+q (16 gate-channels = f-channels [q*16,(q+1)*16)).
// Each wave computes 96 pixels (2 rows) x 16 channels: Mrep=6, Nrep=1.
// Weight fragment reuse = 96 pixels/fetch (2x round-7) -> MFMA-bound.
// SWZ: XOR-swizzled LDS patch (requires pow-2 channel stride); else padded.
// FIRST: h_prev = c_prev = 0.  STATS: BN sum/sumsq + seqOut.  BNIN: normalize
// A-channels while staging (in-bounds pixels only).  OUT: h,c -> outF (f32).
// ---------------------------------------------------------------------------
template<int CIN_A, int CPAD, bool SWZ, bool FIRST, bool STATS, bool BNIN, bool OUT>
__global__ __launch_bounds__(256) void convlstm_step(
    const ushort* __restrict__ inA, long strideA,   // per-img stride (elements)
    const ushort* __restrict__ inB,                 // h_prev (B,2304,64) bf16
    const ushort* __restrict__ Wsw,                 // swizzled [ntile][KS][64][8]
    const float*  __restrict__ bias,                // (256)
    float*  __restrict__ cState,                    // (B,2304,64) f32 in place
    ushort* __restrict__ hOut,                      // (B,2304,64) bf16
    ushort* __restrict__ seqOut,                    // STATS only
    float*  __restrict__ stats,                     // [128]
    const float* __restrict__ gamma,
    const float* __restrict__ beta,
    float*  __restrict__ outF)                      // OUT only
{
    constexpr int CIN_TOT = CIN_A + 64;
    constexpr int K   = 9 * CIN_TOT;
    constexpr int KS  = (K + 31) / 32;
    constexpr int KP  = KS * 32;
    constexpr int PATCHB = 4 * 50 * CPAD * 2;        // 4 rows (2 out rows + halo)
    constexpr int GBUFB  = 96 * 68 * 4;              // 26,112
    constexpr int SMEMB  = PATCHB > GBUFB ? PATCHB : GBUFB;
    __shared__ __align__(16) unsigned char smem[SMEMB];
    __shared__ float sred[4][2][16];
    __shared__ float bnsc[64], bnsh[64];

    const int bid = blockIdx.x;
    const int img = bid / 96;
    const int rem = bid % 96;
    const int y2  = rem >> 2;          // row pair 0..23
    const int q   = rem & 3;           // f-quarter 0..3
    const int tid = threadIdx.x, wid = tid >> 6, l = tid & 63;
    const int lm = l & 15, lk8 = (l >> 4) * 8;

    if constexpr (BNIN) {
        if (tid < 64) {
            const float mean = stats[tid] * BN_INVN;
            const float var  = stats[64 + tid] * BN_INVN - mean * mean;
            const float sc   = gamma[tid] * rsqrtf(var + 1e-3f);
            bnsc[tid] = sc;
            bnsh[tid] = beta[tid] - mean * sc;
        }
        __syncthreads();
    }

    // byte offset into the LDS patch for (patch row r, staged col dc, chan ci0)
    auto lds_off = [&](int r, int dc, int ci0) -> int {
        int byte = ((r * 50 + dc) * CPAD + ci0) * 2;
        if constexpr (SWZ) byte ^= (dc & 7) << 4;
        return byte;
    };

    // ---- stage 4 x 50 x CIN_TOT patch (zero-padded) ----
    const ushort* aBase = inA + (size_t)img * strideA;
    const ushort* bBase = inB + (size_t)img * IMGPIX * 64;
    constexpr int CA8 = CIN_A / 8;
    for (int e = tid; e < 4 * 48 * CA8; e += 256) {           // x/seq channels
        const int r = e / (48 * CA8), qq = e % (48 * CA8);
        const int col = qq / CA8, ci0 = (qq % CA8) * 8;
        const int gy = y2 * 2 + r - 1;
        uint4 v = make_uint4(0, 0, 0, 0);
        if (gy >= 0 && gy < 48) {
            v = *(const uint4*)(aBase + ((size_t)gy * 48 + col) * CIN_A + ci0);
            if constexpr (BNIN) {      // BN only on real pixels; padding stays 0
                ushort* u = (ushort*)&v;
#pragma unroll
                for (int j = 0; j < 8; ++j)
                    u[j] = f2b(b2f(u[j]) * bnsc[ci0 + j] + bnsh[ci0 + j]);
            }
        }
        *(uint4*)(smem + lds_off(r, col + 1, ci0)) = v;
    }
    for (int e = tid; e < 4 * 48 * 8; e += 256) {             // h channels
        const int r = e / (48 * 8), qq = e % (48 * 8);
        const int col = qq / 8, ci0 = (qq % 8) * 8;
        uint4 v = make_uint4(0, 0, 0, 0);
        if constexpr (!FIRST) {
            const int gy = y2 * 2 + r - 1;
            if (gy >= 0 && gy < 48)
                v = *(const uint4*)(bBase + ((size_t)gy * 48 + col) * 64 + ci0);
        }
        *(uint4*)(smem + lds_off(r, col + 1, CIN_A + ci0)) = v;
    }
    constexpr int CT8 = CIN_TOT / 8;
    for (int e = tid; e < 4 * 2 * CT8; e += 256) {            // pad cols 0 and 49
        const int r = e / (2 * CT8), qq = e % (2 * CT8);
        const int dc = (qq / CT8) ? 49 : 0, ci0 = (qq % CT8) * 8;
        *(uint4*)(smem + lds_off(r, dc, ci0)) = make_uint4(0, 0, 0, 0);
    }
    __syncthreads();

    // ---- MFMA: 96 pixels x 16 channels, K = 9*CIN_TOT ----
    const int ntile = wid * 4 + q;           // gate wid, f-quarter q
    f32x4 acc[6] = {};

#pragma unroll
    for (int ks = 0; ks < KS; ++ks) {
        V16 bf;
        bf.u = *(const uint4*)(Wsw + ((size_t)(ntile * KS + ks) * 64 + l) * 8);
        const int k   = ks * 32 + lk8;
        const int tap = k / CIN_TOT, ci0 = k % CIN_TOT;
        const int ky  = tap / 3, kx = tap - 3 * (tap / 3);
        V16 af[6];
#pragma unroll
        for (int m = 0; m < 6; ++m) {
            const int sr = (m < 3) ? 0 : 1;          // strip row
            const int fm = (m < 3) ? m : m - 3;      // frag within row
            const int dcc = fm * 16 + lm + kx;
            uint4 v = *(const uint4*)(smem + lds_off(sr + ky, dcc, ci0));
            if (KP > K && ks == KS - 1 && k >= K) v = make_uint4(0, 0, 0, 0);
            af[m].u = v;
        }
#pragma unroll
        for (int m = 0; m < 6; ++m)
            acc[m] = __builtin_amdgcn_mfma_f32_16x16x32_bf16(af[m].b, bf.b, acc[m], 0, 0, 0);
    }

    // ---- epilogue: gates -> LSTM state update (16 f-channels, 96 pixels) ----
    __syncthreads();                       // patch region now dead
    float* gbuf = (float*)smem;            // [96][68] f32
    const float bv = bias[wid * 64 + q * 16 + lm];
#pragma unroll
    for (int m = 0; m < 6; ++m)
#pragma unroll
        for (int r = 0; r < 4; ++r) {
            const int pixel = m * 16 + (l >> 4) * 4 + r;
            gbuf[pixel * 68 + wid * 16 + lm] = acc[m][r] + bv;
        }
    __syncthreads();

    float s1 = 0.f, s2 = 0.f;
    const size_t rowBase = (size_t)img * IMGPIX + (size_t)y2 * 96;
#pragma unroll
    for (int it = 0; it < 6; ++it) {
        const int idx = it * 256 + tid;
        const int p = idx >> 4, fr = idx & 15;     // fr fixed per thread
        const float gi = gbuf[p * 68 + fr];
        const float gf = gbuf[p * 68 + 16 + fr];
        const float gc = gbuf[p * 68 + 32 + fr];
        const float go = gbuf[p * 68 + 48 + fr];
        const size_t off = (rowBase + p) * 64 + q * 16 + fr;
        const float cold = FIRST ? 0.f : cState[off];
        const float cn = hsig(gf) * cold + hsig(gi) * tanh_f(gc);
        const float hn = hsig(go) * tanh_f(cn);
        cState[off] = cn;
        hOut[off]   = f2b(hn);
        if constexpr (STATS) { seqOut[off] = f2b(hn); s1 += hn; s2 += hn * hn; }
        if constexpr (OUT)   { outF[off] = hn; outF[STATE_ELEMS + off] = cn; }
    }

    if constexpr (STATS) {
        s1 += __shfl_xor(s1, 16);  s2 += __shfl_xor(s2, 16);
        s1 += __shfl_xor(s1, 32);  s2 += __shfl_xor(s2, 32);
        if (l < 16) { sred[wid][0][l] = s1; sred[wid][1][l] = s2; }
        __syncthreads();
        if (tid < 32) {
            const int kind = tid >> 4, fr = tid & 15;
            const float v = sred[0][kind][fr] + sred[1][kind][fr]
                          + sred[2][kind][fr] + sred[3][kind][fr];
            atomicAdd(&stats[kind * 64 + q * 16 + fr], v);
        }
    }
}

// ---------------------------------------------------------------------------
// One-shot prep: cast x to bf16, build both swizzled concat weights, zero stats.
// Weight layout: out[((ntile*KS+ks)*64+l)*8+j] = Wcat[k][n], n = ntile*16+(l&15),
// k = ks*32+((l>>4)&3)*8+j; Wcat k-order tap-major, ci = [x-ch | h-ch].
// ---------------------------------------------------------------------------
__device__ __forceinline__ ushort swz_elem(
    const float* __restrict__ Wx, const float* __restrict__ Wh,
    int CIN_A, int KS, int idx)
{
    const int K = 9 * (CIN_A + 64);
    const int j = idx & 7, lw = (idx >> 3) & 63, rest = idx >> 9;
    const int ks = rest % KS, ntile = rest / KS;
    const int n = ntile * 16 + (lw & 15);
    const int k = ks * 32 + ((lw >> 4) & 3) * 8 + j;
    if (k >= K) return (ushort)0;
    const int CT = CIN_A + 64;
    const int tap = k / CT, ci = k % CT;
    const float v = (ci < CIN_A) ? Wx[((size_t)tap * CIN_A + ci) * CO + n]
                                 : Wh[((size_t)tap * 64 + (ci - CIN_A)) * CO + n];
    return f2b(v);
}

__global__ __launch_bounds__(256) void prep_kernel(
    const float* __restrict__ x,
    const float* __restrict__ Wx1, const float* __restrict__ Wh1,
    const float* __restrict__ Wx2, const float* __restrict__ Wh2,
    ushort* __restrict__ xb, ushort* __restrict__ wc1, ushort* __restrict__ wc2,
    float* __restrict__ stats)
{
    constexpr int N0 = 368640;          // x: 2,949,120 elems / 8
    constexpr int N1 = 16 * 23 * 512;   // 188,416
    constexpr int N2 = 16 * 36 * 512;   // 294,912
    const int gid = blockIdx.x * 256 + threadIdx.x;
    if (gid < N0) {
        const float4 a = ((const float4*)x)[(size_t)gid * 2];
        const float4 b = ((const float4*)x)[(size_t)gid * 2 + 1];
        ushort o[8] = { f2b(a.x), f2b(a.y), f2b(a.z), f2b(a.w),
                        f2b(b.x), f2b(b.y), f2b(b.z), f2b(b.w) };
        *(uint4*)(xb + (size_t)gid * 8) = *(const uint4*)o;
    } else if (gid < N0 + N1) {
        wc1[gid - N0] = swz_elem(Wx1, Wh1, 16, 23, gid - N0);
    } else if (gid < N0 + N1 + N2) {
        wc2[gid - N0 - N1] = swz_elem(Wx2, Wh2, 64, 36, gid - N0 - N1);
    } else if (gid < N0 + N1 + N2 + 128) {
        stats[gid - N0 - N1 - N2] = 0.f;
    }
}

// ---------------------------------------------------------------------------
extern "C" void kernel_launch(void* const* d_in, const int* in_sizes, int n_in,
                              void* d_out, int out_size, void* d_ws, size_t ws_size,
                              hipStream_t stream)
{
    const float* x      = (const float*)d_in[0];
    const float* Wx1    = (const float*)d_in[1];
    const float* Wh1    = (const float*)d_in[2];
    const float* b1     = (const float*)d_in[3];
    const float* gamma1 = (const float*)d_in[4];
    const float* beta1  = (const float*)d_in[5];
    const float* Wx2    = (const float*)d_in[6];
    const float* Wh2    = (const float*)d_in[7];
    const float* b2     = (const float*)d_in[8];

    // workspace layout (bytes) -- ~49 MB of the 256 MB ws
    unsigned char* w = (unsigned char*)d_ws;
    ushort* seq1 = (ushort*)w;  w += 23592960;   // (T,B,2304,64) bf16
    ushort* xb   = (ushort*)w;  w += 5898240;    // (B,T,2304,16) bf16
    ushort* wc1  = (ushort*)w;  w += 376832;     // 16*23*512 u16
    ushort* wc2  = (ushort*)w;  w += 589824;     // 16*36*512 u16
    ushort* hb1a = (ushort*)w;  w += 2359296;
    ushort* hb1b = (ushort*)w;  w += 2359296;
    ushort* hb2a = (ushort*)w;  w += 2359296;
    ushort* hb2b = (ushort*)w;  w += 2359296;
    float*  c1   = (float*)w;   w += 4718592;
    float*  c2   = (float*)w;   w += 4718592;
    float*  stats = (float*)w;  w += 512;

    prep_kernel<<<3329, 256, 0, stream>>>(x, Wx1, Wh1, Wx2, Wh2, xb, wc1, wc2, stats);

    const long xStride = (long)T * IMGPIX * 16;
    ushort* hp1[2] = { hb1a, hb1b };

    // ----- layer 1: CIN_A=16, CPAD=88 (padded; 176B stride, non-pow2 -> no XOR)
    convlstm_step<16, 88, false, true, true, false, false><<<768, 256, 0, stream>>>(
        xb, xStride, hp1[0], wc1, b1, c1, hp1[1],
        seq1, stats, nullptr, nullptr, nullptr);
    for (int t = 1; t < 9; ++t)
        convlstm_step<16, 88, false, false, true, false, false><<<768, 256, 0, stream>>>(
            xb + (size_t)t * IMGPIX * 16, xStride, hp1[t & 1], wc1, b1, c1, hp1[(t + 1) & 1],
            seq1 + (size_t)t * STATE_ELEMS, stats, nullptr, nullptr, nullptr);
    convlstm_step<16, 88, false, false, true, false, true><<<768, 256, 0, stream>>>(
        xb + (size_t)9 * IMGPIX * 16, xStride, hp1[1], wc1, b1, c1, hp1[0],
        seq1 + (size_t)9 * STATE_ELEMS, stats, nullptr, nullptr, (float*)d_out);

    // ----- layer 2: CIN_A=64, CPAD=128 (pow-2 stride -> bijective XOR swizzle)
    ushort* hp2[2] = { hb2a, hb2b };
    convlstm_step<64, 128, true, true, false, true, false><<<768, 256, 0, stream>>>(
        seq1, IMGPIX * 64, hp2[0], wc2, b2, c2, hp2[1],
        nullptr, stats, gamma1, beta1, nullptr);
    for (int t = 1; t < 9; ++t)
        convlstm_step<64, 128, true, false, false, true, false><<<768, 256, 0, stream>>>(
            seq1 + (size_t)t * STATE_ELEMS, IMGPIX * 64, hp2[t & 1], wc2, b2, c2, hp2[(t + 1) & 1],
            nullptr, stats, gamma1, beta1, nullptr);
    convlstm_step<64, 128, true, false, false, true, true><<<768, 256, 0, stream>>>(
        seq1 + (size_t)9 * STATE_ELEMS, IMGPIX * 64, hp2[1], wc2, b2, c2, hp2[0],
        nullptr, stats, gamma1, beta1, (float*)d_out + 2 * STATE_ELEMS);
}